// Round 4
// baseline (2254.326 us; speedup 1.0000x reference)
//
#include <hip/hip_runtime.h>

typedef unsigned int uint_t;

#define SEQ 15
#define BATCH 32
#define NNODES 5000
#define NEDGES 80000
#define INFEAT 16
#define HID 512
#define G3 1536   // 3*HID
#define GRU_BLOCKS 256
#define NGRP 16
#define GRPSZ (GRU_BLOCKS / NGRP)   // 16
#define BAR_INTS (32 * (NGRP + 2 + NGRP))   // group counters | top | gen | group gens

__device__ __forceinline__ float sigmoidf(float x){ return 1.0f / (1.0f + __expf(-x)); }

// ---------------- init ----------------
__global__ void k_init(int* counts, int* fill, int* bar,
                       float* h0a, float* h0b, float* h1a, float* h1b){
    int t = blockIdx.x * 256 + threadIdx.x;   // 0..16383
    if (t < NNODES){ counts[t] = 0; fill[t] = 0; }
    if (t < BAR_INTS) bar[t] = 0;
    h0a[t] = 0.f; h0b[t] = 0.f; h1a[t] = 0.f; h1b[t] = 0.f;
}

// ---------------- degree count (by target col) ----------------
__global__ void k_count(const int* ei, int* counts){
    int e = blockIdx.x * 256 + threadIdx.x;
    if (e < NEDGES) atomicAdd(&counts[ei[NEDGES + e]], 1);
}

__global__ void k_dinv(const int* counts, float* dinv){
    int n = blockIdx.x * 256 + threadIdx.x;
    if (n < NNODES) dinv[n] = rsqrtf(1.0f + (float)counts[n]);  // +1 self loop
}

// ---------------- exclusive scan of counts -> offs (single block) ----------------
__global__ void k_scan(const int* counts, int* offs){
    __shared__ int sdata[1024];
    int tid = threadIdx.x;
    int base = tid * 5;
    int loc[5]; int tot = 0;
    #pragma unroll
    for (int q = 0; q < 5; q++){
        int idx = base + q;
        int v = (idx < NNODES) ? counts[idx] : 0;
        loc[q] = tot; tot += v;
    }
    sdata[tid] = tot; __syncthreads();
    for (int off = 1; off < 1024; off <<= 1){
        int t = (tid >= off) ? sdata[tid - off] : 0;
        __syncthreads();
        sdata[tid] += t;
        __syncthreads();
    }
    int excl = sdata[tid] - tot;
    #pragma unroll
    for (int q = 0; q < 5; q++){
        int idx = base + q;
        if (idx < NNODES) offs[idx] = excl + loc[q];
    }
    if (tid == 1023) offs[NNODES] = sdata[1023];
}

// ---------------- CSR fill: bucket sources by target ----------------
__global__ void k_fill(const int* ei, const int* offs, int* fill, int* csr){
    int e = blockIdx.x * 256 + threadIdx.x;
    if (e < NEDGES){
        int c = ei[NEDGES + e];
        int p = offs[c] + atomicAdd(&fill[c], 1);
        csr[p] = ei[e];
    }
}

// ---------------- conv1 linear: h1s[s,b,n,{0,1}] = dinv[n] * (x[s,b,n,:] @ W1[s]) ----------------
__global__ void k_conv1(const float* x, const float* W1, const float* dinv, float* h1s){
    int n = blockIdx.x * 256 + threadIdx.x;
    int b = blockIdx.y, s = blockIdx.z;
    if (n >= NNODES) return;
    float w[32];
    #pragma unroll
    for (int q = 0; q < 32; q++) w[q] = W1[s * 32 + q];   // s uniform -> scalar loads
    size_t idx = ((size_t)(s * BATCH + b) * NNODES + n);
    const float4* xp = (const float4*)(x + idx * INFEAT);
    float4 u0 = xp[0], u1 = xp[1], u2 = xp[2], u3 = xp[3];
    float xs[16] = { u0.x,u0.y,u0.z,u0.w, u1.x,u1.y,u1.z,u1.w,
                     u2.x,u2.y,u2.z,u2.w, u3.x,u3.y,u3.z,u3.w };
    float a0 = 0.f, a1 = 0.f;
    #pragma unroll
    for (int f = 0; f < 16; f++){ a0 += xs[f] * w[2 * f]; a1 += xs[f] * w[2 * f + 1]; }
    float d = dinv[n];
    ((float2*)h1s)[idx] = make_float2(d * a0, d * a1);
}

// ------- aggregate1 + bias + relu + conv2 linear + pre-scale: h2s = dinv * (relu(dinv*agg + b1) @ W2) -------
__global__ void k_agg1(const float* h1s, const int* offs, const int* csr, const float* dinv,
                       const float* b1, const float* W2, float* h2s){
    int n = blockIdx.x * 256 + threadIdx.x;
    int b = blockIdx.y, s = blockIdx.z;
    if (n >= NNODES) return;
    size_t base = (size_t)(s * BATCH + b) * NNODES;
    const float2* hp = (const float2*)h1s + base;
    float2 self = hp[n];
    float a0 = self.x, a1 = self.y;
    int p1 = offs[n + 1];
    for (int p = offs[n]; p < p1; p++){
        float2 v = hp[csr[p]];
        a0 += v.x; a1 += v.y;
    }
    float d = dinv[n];
    float r0 = fmaxf(d * a0 + b1[s * 2 + 0], 0.f);
    float r1 = fmaxf(d * a1 + b1[s * 2 + 1], 0.f);
    float t2 = r0 * W2[s * 2 + 0] + r1 * W2[s * 2 + 1];
    h2s[base + n] = d * t2;
}

// ------- aggregate2 + bias + tanh -> g[s*32+b][n] -------
__global__ void k_agg2(const float* h2s, const int* offs, const int* csr, const float* dinv,
                       const float* b2, float* g){
    int n = blockIdx.x * 256 + threadIdx.x;
    int b = blockIdx.y, s = blockIdx.z;
    if (n >= NNODES) return;
    size_t base = (size_t)(s * BATCH + b) * NNODES;
    const float* hp = h2s + base;
    float a = hp[n];
    int p1 = offs[n + 1];
    for (int p = offs[n]; p < p1; p++) a += hp[csr[p]];
    g[base + n] = tanhf(dinv[n] * a + b2[s]);
}

// ------- GEMM: gi0[480][1536] = g[480][5000] @ w_ih0[1536][5000]^T + b_ih0 (fp32) -------
__global__ __launch_bounds__(256) void k_gemm(const float* A, const float* W,
                                              const float* bias, float* C){
    __shared__ float As[16 * 64];
    __shared__ float Bs[16 * 64];
    int tid = threadIdx.x;
    int j0 = blockIdx.x * 64;   // N tile (1536/64 = 24)
    int m0 = blockIdx.y * 64;   // M tile (ceil(480/64) = 8)
    int tm = tid >> 4, tn = tid & 15;
    int lr = tid >> 2;           // 0..63
    int lk = (tid & 3) * 4;      // 0,4,8,12
    float acc[4][4];
    #pragma unroll
    for (int i = 0; i < 4; i++)
        #pragma unroll
        for (int j = 0; j < 4; j++) acc[i][j] = 0.f;

    for (int k0 = 0; k0 < 5000; k0 += 16){
        int m = m0 + lr;
        float4 av = make_float4(0.f, 0.f, 0.f, 0.f);
        if (m < 480 && (k0 + lk) < 5000)
            av = *(const float4*)&A[(size_t)m * 5000 + k0 + lk];
        As[(lk + 0) * 64 + lr] = av.x; As[(lk + 1) * 64 + lr] = av.y;
        As[(lk + 2) * 64 + lr] = av.z; As[(lk + 3) * 64 + lr] = av.w;
        int j = j0 + lr;
        float4 bv = make_float4(0.f, 0.f, 0.f, 0.f);
        if ((k0 + lk) < 5000)
            bv = *(const float4*)&W[(size_t)j * 5000 + k0 + lk];
        Bs[(lk + 0) * 64 + lr] = bv.x; Bs[(lk + 1) * 64 + lr] = bv.y;
        Bs[(lk + 2) * 64 + lr] = bv.z; Bs[(lk + 3) * 64 + lr] = bv.w;
        __syncthreads();
        #pragma unroll
        for (int k = 0; k < 16; k++){
            float4 a = *(float4*)&As[k * 64 + tm * 4];
            float4 bb = *(float4*)&Bs[k * 64 + tn * 4];
            acc[0][0] += a.x * bb.x; acc[0][1] += a.x * bb.y; acc[0][2] += a.x * bb.z; acc[0][3] += a.x * bb.w;
            acc[1][0] += a.y * bb.x; acc[1][1] += a.y * bb.y; acc[1][2] += a.y * bb.z; acc[1][3] += a.y * bb.w;
            acc[2][0] += a.z * bb.x; acc[2][1] += a.z * bb.y; acc[2][2] += a.z * bb.z; acc[2][3] += a.z * bb.w;
            acc[3][0] += a.w * bb.x; acc[3][1] += a.w * bb.y; acc[3][2] += a.w * bb.z; acc[3][3] += a.w * bb.w;
        }
        __syncthreads();
    }
    #pragma unroll
    for (int i = 0; i < 4; i++){
        int m = m0 + tm * 4 + i;
        if (m < 480){
            #pragma unroll
            for (int j = 0; j < 4; j++){
                int col = j0 + tn * 4 + j;
                C[(size_t)m * G3 + col] = acc[i][j] + bias[col];
            }
        }
    }
}

// ------- hierarchical grid barrier --------------------------------------------
// Round-3 profile: flat barrier (256 RMWs on ONE line) cost ~33 us each; 30
// barriers = ~95% of k_gru's 985 us. Two-level tree: 16 arrival lines x 16
// RMWs in parallel, 16 leaders poll global gen, members poll per-group line.
__device__ __forceinline__ void grid_barrier(int* bar){
    __syncthreads();
    if (threadIdx.x == 0){
        const int g = blockIdx.x & (NGRP - 1);
        int* garr = &bar[32 * g];                 // group arrival counter (own line)
        int* top  = &bar[32 * NGRP];              // top-level counter
        int* gen  = &bar[32 * (NGRP + 1)];        // global generation
        int* gg   = &bar[32 * (NGRP + 2 + g)];    // per-group broadcast gen (own line)
        int myg = __hip_atomic_load(gen, __ATOMIC_RELAXED, __HIP_MEMORY_SCOPE_AGENT);
        __threadfence();
        int a = __hip_atomic_fetch_add(garr, 1, __ATOMIC_ACQ_REL, __HIP_MEMORY_SCOPE_AGENT);
        if (a == GRPSZ - 1){
            __hip_atomic_store(garr, 0, __ATOMIC_RELAXED, __HIP_MEMORY_SCOPE_AGENT);
            int t = __hip_atomic_fetch_add(top, 1, __ATOMIC_ACQ_REL, __HIP_MEMORY_SCOPE_AGENT);
            if (t == NGRP - 1){
                __hip_atomic_store(top, 0, __ATOMIC_RELAXED, __HIP_MEMORY_SCOPE_AGENT);
                __hip_atomic_fetch_add(gen, 1, __ATOMIC_RELEASE, __HIP_MEMORY_SCOPE_AGENT);
            }
            while (__hip_atomic_load(gen, __ATOMIC_ACQUIRE, __HIP_MEMORY_SCOPE_AGENT) == myg)
                __builtin_amdgcn_s_sleep(2);
            __hip_atomic_store(gg, myg + 1, __ATOMIC_RELEASE, __HIP_MEMORY_SCOPE_AGENT);
        } else {
            while (__hip_atomic_load(gg, __ATOMIC_ACQUIRE, __HIP_MEMORY_SCOPE_AGENT) != myg + 1)
                __builtin_amdgcn_s_sleep(2);
        }
        __threadfence();
    }
    __syncthreads();
}

__global__ __launch_bounds__(256) void k_gru(
        const float* gi0,
        const float* wih1, const float* whh0, const float* whh1,
        const float* bih1, const float* bhh0, const float* bhh1,
        float* h0a, float* h0b, float* h1a, float* h1b,
        float* out, int* bar){
    __shared__ float wh0[6 * HID];
    __shared__ float wi1[6 * HID];
    __shared__ float wh1[6 * HID];
    __shared__ float part[12 * 8 * 32];
    __shared__ float ghl[12 * 32];

    int tid = threadIdx.x;
    int i0 = blockIdx.x * 2;

    // stage this block's 6 rows of each weight matrix (rows j = gate*512 + i0 + l)
    #pragma unroll
    for (int r = 0; r < 6; r++){
        int j = (r >> 1) * HID + i0 + (r & 1);
        for (int k = tid; k < HID; k += 256){
            wh0[r * HID + k] = whh0[(size_t)j * HID + k];
            wi1[r * HID + k] = wih1[(size_t)j * HID + k];
            wh1[r * HID + k] = whh1[(size_t)j * HID + k];
        }
    }
    __syncthreads();

    int b = tid & 31, ks = tid >> 5;   // batch lane, k-slice (8 slices of 64)
    int k0 = ks * 64;
    float* h0r = h0a; float* h0w = h0b;
    float* h1r = h1a; float* h1w = h1b;

    for (int s = 0; s < SEQ; s++){
        // ---- phase A: layer0 gh = h0 @ whh0^T (this block's 6 rows) ----
        {
            float p[6] = {0.f,0.f,0.f,0.f,0.f,0.f};
            for (int kk = 0; kk < 64; kk += 4){
                int k = k0 + kk;
                float h0v = h0r[(k + 0) * 32 + b];
                float h1v = h0r[(k + 1) * 32 + b];
                float h2v = h0r[(k + 2) * 32 + b];
                float h3v = h0r[(k + 3) * 32 + b];
                #pragma unroll
                for (int r = 0; r < 6; r++){
                    float4 w = *(float4*)&wh0[r * HID + k];
                    p[r] += h0v * w.x + h1v * w.y + h2v * w.z + h3v * w.w;
                }
            }
            #pragma unroll
            for (int r = 0; r < 6; r++) part[(r * 8 + ks) * 32 + b] = p[r];
        }
        __syncthreads();
        if (tid < 192){
            int r = tid >> 5, bb = tid & 31;
            float sum = 0.f;
            #pragma unroll
            for (int q = 0; q < 8; q++) sum += part[(r * 8 + q) * 32 + bb];
            ghl[r * 32 + bb] = sum;
        }
        __syncthreads();
        if (tid < 64){
            int l = tid >> 5, bb = tid & 31;
            int i = i0 + l;
            const float* gi = gi0 + (size_t)(s * BATCH + bb) * G3;
            float ghr = ghl[(0 + l) * 32 + bb] + bhh0[i];
            float ghz = ghl[(2 + l) * 32 + bb] + bhh0[HID + i];
            float ghn = ghl[(4 + l) * 32 + bb] + bhh0[2 * HID + i];
            float rr = sigmoidf(gi[i] + ghr);
            float zz = sigmoidf(gi[HID + i] + ghz);
            float nn = tanhf(gi[2 * HID + i] + rr * ghn);
            float hold = h0r[i * 32 + bb];
            h0w[i * 32 + bb] = (1.f - zz) * nn + zz * hold;
        }
        grid_barrier(bar);

        // ---- phase B: layer1 gi1 = out1_s @ wih1^T, gh1 = h1 @ whh1^T ----
        {
            float pi[6] = {0.f,0.f,0.f,0.f,0.f,0.f};
            float ph[6] = {0.f,0.f,0.f,0.f,0.f,0.f};
            for (int kk = 0; kk < 64; kk += 4){
                int k = k0 + kk;
                float o0 = h0w[(k + 0) * 32 + b];
                float o1 = h0w[(k + 1) * 32 + b];
                float o2 = h0w[(k + 2) * 32 + b];
                float o3 = h0w[(k + 3) * 32 + b];
                float v0 = h1r[(k + 0) * 32 + b];
                float v1 = h1r[(k + 1) * 32 + b];
                float v2 = h1r[(k + 2) * 32 + b];
                float v3 = h1r[(k + 3) * 32 + b];
                #pragma unroll
                for (int r = 0; r < 6; r++){
                    float4 wi = *(float4*)&wi1[r * HID + k];
                    float4 wh = *(float4*)&wh1[r * HID + k];
                    pi[r] += o0 * wi.x + o1 * wi.y + o2 * wi.z + o3 * wi.w;
                    ph[r] += v0 * wh.x + v1 * wh.y + v2 * wh.z + v3 * wh.w;
                }
            }
            #pragma unroll
            for (int r = 0; r < 6; r++){
                part[(r * 8 + ks) * 32 + b] = pi[r];
                part[((6 + r) * 8 + ks) * 32 + b] = ph[r];
            }
        }
        __syncthreads();
        {
            // 12 rows to reduce with 256 threads (8 rows/pass): loop r += 8.
            int bb = tid & 31;
            for (int r = tid >> 5; r < 12; r += 8){
                float sum = 0.f;
                #pragma unroll
                for (int q = 0; q < 8; q++) sum += part[(r * 8 + q) * 32 + bb];
                ghl[r * 32 + bb] = sum;
            }
        }
        __syncthreads();
        if (tid < 64){
            int l = tid >> 5, bb = tid & 31;
            int i = i0 + l;
            float gir = ghl[(0 + l) * 32 + bb] + bih1[i];
            float giz = ghl[(2 + l) * 32 + bb] + bih1[HID + i];
            float gin = ghl[(4 + l) * 32 + bb] + bih1[2 * HID + i];
            float ghr = ghl[(6 + l) * 32 + bb] + bhh1[i];
            float ghz = ghl[(8 + l) * 32 + bb] + bhh1[HID + i];
            float ghn = ghl[(10 + l) * 32 + bb] + bhh1[2 * HID + i];
            float rr = sigmoidf(gir + ghr);
            float zz = sigmoidf(giz + ghz);
            float nn = tanhf(gin + rr * ghn);
            float hold = h1r[i * 32 + bb];
            float hnew = (1.f - zz) * nn + zz * hold;
            h1w[i * 32 + bb] = hnew;
            out[(size_t)(s * BATCH + bb) * HID + i] = hnew;   // out2[s,b,i]
        }
        grid_barrier(bar);

        { float* t = h0r; h0r = h0w; h0w = t; }
        { float* t = h1r; h1r = h1w; h1w = t; }
    }

    // hn: [0]=h0 final, [1]=h1 final (own rows only — written by this block)
    if (tid < 64){
        int l = tid >> 5, bb = tid & 31;
        int i = i0 + l;
        out[SEQ * BATCH * HID + (size_t)bb * HID + i] = h0r[i * 32 + bb];
        out[SEQ * BATCH * HID + BATCH * HID + (size_t)bb * HID + i] = h1r[i * 32 + bb];
    }
}

extern "C" void kernel_launch(void* const* d_in, const int* in_sizes, int n_in,
                              void* d_out, int out_size, void* d_ws, size_t ws_size,
                              hipStream_t stream){
    (void)in_sizes; (void)n_in; (void)out_size; (void)ws_size;
    const float* x    = (const float*)d_in[0];
    const int*   ei   = (const int*)d_in[1];
    const float* W1   = (const float*)d_in[2];
    const float* b1   = (const float*)d_in[3];
    const float* W2   = (const float*)d_in[4];
    const float* b2   = (const float*)d_in[5];
    const float* wih0 = (const float*)d_in[6];
    const float* whh0 = (const float*)d_in[7];
    const float* bih0 = (const float*)d_in[8];
    const float* bhh0 = (const float*)d_in[9];
    const float* wih1 = (const float*)d_in[10];
    const float* whh1 = (const float*)d_in[11];
    const float* bih1 = (const float*)d_in[12];
    const float* bhh1 = (const float*)d_in[13];
    float* out = (float*)d_out;

    char* w = (char*)d_ws;
    auto alloc = [&](size_t bytes) -> char* {
        char* p = w; w += (bytes + 255) & ~(size_t)255; return p;
    };
    float* dinv   = (float*)alloc(NNODES * 4);
    int*   counts = (int*)  alloc(NNODES * 4);
    int*   offs   = (int*)  alloc((NNODES + 8) * 4);
    int*   fill   = (int*)  alloc(NNODES * 4);
    int*   csr    = (int*)  alloc(NEDGES * 4);
    int*   bar    = (int*)  alloc(BAR_INTS * 4);
    float* h0a    = (float*)alloc(HID * BATCH * 4);
    float* h0b    = (float*)alloc(HID * BATCH * 4);
    float* h1a    = (float*)alloc(HID * BATCH * 4);
    float* h1b    = (float*)alloc(HID * BATCH * 4);
    float* h1s    = (float*)alloc((size_t)SEQ * BATCH * NNODES * 2 * 4);
    float* h2s    = (float*)alloc((size_t)SEQ * BATCH * NNODES * 4);
    float* gbuf   = (float*)alloc((size_t)SEQ * BATCH * NNODES * 4);
    float* gi0    = (float*)alloc((size_t)SEQ * BATCH * G3 * 4);

    k_init <<<64, 256, 0, stream>>>(counts, fill, bar, h0a, h0b, h1a, h1b);
    k_count<<<(NEDGES + 255) / 256, 256, 0, stream>>>(ei, counts);
    k_dinv <<<(NNODES + 255) / 256, 256, 0, stream>>>(counts, dinv);
    k_scan <<<1, 1024, 0, stream>>>(counts, offs);
    k_fill <<<(NEDGES + 255) / 256, 256, 0, stream>>>(ei, offs, fill, csr);

    dim3 gconv((NNODES + 255) / 256, BATCH, SEQ);
    k_conv1<<<gconv, 256, 0, stream>>>(x, W1, dinv, h1s);
    k_agg1 <<<gconv, 256, 0, stream>>>(h1s, offs, csr, dinv, b1, W2, h2s);
    k_agg2 <<<gconv, 256, 0, stream>>>(h2s, offs, csr, dinv, b2, gbuf);

    k_gemm<<<dim3(G3 / 64, 8), 256, 0, stream>>>(gbuf, wih0, bih0, gi0);

    k_gru<<<GRU_BLOCKS, 256, 0, stream>>>(gi0, wih1, whh0, whh1, bih1, bhh0, bhh1,
                                          h0a, h0b, h1a, h1b, out, bar);
}

// Round 5
// 1475.410 us; speedup vs baseline: 1.5279x; 1.5279x over previous
//
#include <hip/hip_runtime.h>

typedef unsigned int uint_t;

#define SEQ 15
#define BATCH 32
#define NNODES 5000
#define NEDGES 80000
#define INFEAT 16
#define HID 512
#define G3 1536   // 3*HID
#define GRU_BLOCKS 256
#define BAR_INTS (32 * (2 * GRU_BLOCKS))   // 256 slot lines + 256 flag lines

__device__ __forceinline__ float sigmoidf(float x){ return 1.0f / (1.0f + __expf(-x)); }

// ---------------- init ----------------
__global__ void k_init(int* counts, int* fill, int* bar,
                       float* h0a, float* h0b, float* h1a, float* h1b){
    int t = blockIdx.x * 256 + threadIdx.x;   // 0..16383
    if (t < NNODES){ counts[t] = 0; fill[t] = 0; }
    if (t < BAR_INTS) bar[t] = 0;
    h0a[t] = 0.f; h0b[t] = 0.f; h1a[t] = 0.f; h1b[t] = 0.f;
}

// ---------------- degree count (by target col) ----------------
__global__ void k_count(const int* ei, int* counts){
    int e = blockIdx.x * 256 + threadIdx.x;
    if (e < NEDGES) atomicAdd(&counts[ei[NEDGES + e]], 1);
}

__global__ void k_dinv(const int* counts, float* dinv){
    int n = blockIdx.x * 256 + threadIdx.x;
    if (n < NNODES) dinv[n] = rsqrtf(1.0f + (float)counts[n]);  // +1 self loop
}

// ---------------- exclusive scan of counts -> offs (single block) ----------------
__global__ void k_scan(const int* counts, int* offs){
    __shared__ int sdata[1024];
    int tid = threadIdx.x;
    int base = tid * 5;
    int loc[5]; int tot = 0;
    #pragma unroll
    for (int q = 0; q < 5; q++){
        int idx = base + q;
        int v = (idx < NNODES) ? counts[idx] : 0;
        loc[q] = tot; tot += v;
    }
    sdata[tid] = tot; __syncthreads();
    for (int off = 1; off < 1024; off <<= 1){
        int t = (tid >= off) ? sdata[tid - off] : 0;
        __syncthreads();
        sdata[tid] += t;
        __syncthreads();
    }
    int excl = sdata[tid] - tot;
    #pragma unroll
    for (int q = 0; q < 5; q++){
        int idx = base + q;
        if (idx < NNODES) offs[idx] = excl + loc[q];
    }
    if (tid == 1023) offs[NNODES] = sdata[1023];
}

// ---------------- CSR fill: bucket sources by target ----------------
__global__ void k_fill(const int* ei, const int* offs, int* fill, int* csr){
    int e = blockIdx.x * 256 + threadIdx.x;
    if (e < NEDGES){
        int c = ei[NEDGES + e];
        int p = offs[c] + atomicAdd(&fill[c], 1);
        csr[p] = ei[e];
    }
}

// ---------------- conv1 linear: h1s[s,b,n,{0,1}] = dinv[n] * (x[s,b,n,:] @ W1[s]) ----------------
__global__ void k_conv1(const float* x, const float* W1, const float* dinv, float* h1s){
    int n = blockIdx.x * 256 + threadIdx.x;
    int b = blockIdx.y, s = blockIdx.z;
    if (n >= NNODES) return;
    float w[32];
    #pragma unroll
    for (int q = 0; q < 32; q++) w[q] = W1[s * 32 + q];   // s uniform -> scalar loads
    size_t idx = ((size_t)(s * BATCH + b) * NNODES + n);
    const float4* xp = (const float4*)(x + idx * INFEAT);
    float4 u0 = xp[0], u1 = xp[1], u2 = xp[2], u3 = xp[3];
    float xs[16] = { u0.x,u0.y,u0.z,u0.w, u1.x,u1.y,u1.z,u1.w,
                     u2.x,u2.y,u2.z,u2.w, u3.x,u3.y,u3.z,u3.w };
    float a0 = 0.f, a1 = 0.f;
    #pragma unroll
    for (int f = 0; f < 16; f++){ a0 += xs[f] * w[2 * f]; a1 += xs[f] * w[2 * f + 1]; }
    float d = dinv[n];
    ((float2*)h1s)[idx] = make_float2(d * a0, d * a1);
}

// ------- aggregate1 + bias + relu + conv2 linear + pre-scale: h2s = dinv * (relu(dinv*agg + b1) @ W2) -------
__global__ void k_agg1(const float* h1s, const int* offs, const int* csr, const float* dinv,
                       const float* b1, const float* W2, float* h2s){
    int n = blockIdx.x * 256 + threadIdx.x;
    int b = blockIdx.y, s = blockIdx.z;
    if (n >= NNODES) return;
    size_t base = (size_t)(s * BATCH + b) * NNODES;
    const float2* hp = (const float2*)h1s + base;
    float2 self = hp[n];
    float a0 = self.x, a1 = self.y;
    int p1 = offs[n + 1];
    for (int p = offs[n]; p < p1; p++){
        float2 v = hp[csr[p]];
        a0 += v.x; a1 += v.y;
    }
    float d = dinv[n];
    float r0 = fmaxf(d * a0 + b1[s * 2 + 0], 0.f);
    float r1 = fmaxf(d * a1 + b1[s * 2 + 1], 0.f);
    float t2 = r0 * W2[s * 2 + 0] + r1 * W2[s * 2 + 1];
    h2s[base + n] = d * t2;
}

// ------- aggregate2 + bias + tanh -> g[s*32+b][n] -------
__global__ void k_agg2(const float* h2s, const int* offs, const int* csr, const float* dinv,
                       const float* b2, float* g){
    int n = blockIdx.x * 256 + threadIdx.x;
    int b = blockIdx.y, s = blockIdx.z;
    if (n >= NNODES) return;
    size_t base = (size_t)(s * BATCH + b) * NNODES;
    const float* hp = h2s + base;
    float a = hp[n];
    int p1 = offs[n + 1];
    for (int p = offs[n]; p < p1; p++) a += hp[csr[p]];
    g[base + n] = tanhf(dinv[n] * a + b2[s]);
}

// ------- GEMM: gi0[480][1536] = g[480][5000] @ w_ih0[1536][5000]^T + b_ih0 (fp32) -------
__global__ __launch_bounds__(256) void k_gemm(const float* A, const float* W,
                                              const float* bias, float* C){
    __shared__ float As[16 * 64];
    __shared__ float Bs[16 * 64];
    int tid = threadIdx.x;
    int j0 = blockIdx.x * 64;   // N tile (1536/64 = 24)
    int m0 = blockIdx.y * 64;   // M tile (ceil(480/64) = 8)
    int tm = tid >> 4, tn = tid & 15;
    int lr = tid >> 2;           // 0..63
    int lk = (tid & 3) * 4;      // 0,4,8,12
    float acc[4][4];
    #pragma unroll
    for (int i = 0; i < 4; i++)
        #pragma unroll
        for (int j = 0; j < 4; j++) acc[i][j] = 0.f;

    for (int k0 = 0; k0 < 5000; k0 += 16){
        int m = m0 + lr;
        float4 av = make_float4(0.f, 0.f, 0.f, 0.f);
        if (m < 480 && (k0 + lk) < 5000)
            av = *(const float4*)&A[(size_t)m * 5000 + k0 + lk];
        As[(lk + 0) * 64 + lr] = av.x; As[(lk + 1) * 64 + lr] = av.y;
        As[(lk + 2) * 64 + lr] = av.z; As[(lk + 3) * 64 + lr] = av.w;
        int j = j0 + lr;
        float4 bv = make_float4(0.f, 0.f, 0.f, 0.f);
        if ((k0 + lk) < 5000)
            bv = *(const float4*)&W[(size_t)j * 5000 + k0 + lk];
        Bs[(lk + 0) * 64 + lr] = bv.x; Bs[(lk + 1) * 64 + lr] = bv.y;
        Bs[(lk + 2) * 64 + lr] = bv.z; Bs[(lk + 3) * 64 + lr] = bv.w;
        __syncthreads();
        #pragma unroll
        for (int k = 0; k < 16; k++){
            float4 a = *(float4*)&As[k * 64 + tm * 4];
            float4 bb = *(float4*)&Bs[k * 64 + tn * 4];
            acc[0][0] += a.x * bb.x; acc[0][1] += a.x * bb.y; acc[0][2] += a.x * bb.z; acc[0][3] += a.x * bb.w;
            acc[1][0] += a.y * bb.x; acc[1][1] += a.y * bb.y; acc[1][2] += a.y * bb.z; acc[1][3] += a.y * bb.w;
            acc[2][0] += a.z * bb.x; acc[2][1] += a.z * bb.y; acc[2][2] += a.z * bb.z; acc[2][3] += a.z * bb.w;
            acc[3][0] += a.w * bb.x; acc[3][1] += a.w * bb.y; acc[3][2] += a.w * bb.z; acc[3][3] += a.w * bb.w;
        }
        __syncthreads();
    }
    #pragma unroll
    for (int i = 0; i < 4; i++){
        int m = m0 + tm * 4 + i;
        if (m < 480){
            #pragma unroll
            for (int j = 0; j < 4; j++){
                int col = j0 + tn * 4 + j;
                C[(size_t)m * G3 + col] = acc[i][j] + bias[col];
            }
        }
    }
}

// ------- contention-free grid barrier -----------------------------------------
// R3/R4 evidence: polled SHARED lines cost ~5 us per observe-hop (flat 256: ~33
// us; hierarchical added one hop -> +4.8 us). Here: zero RMWs, zero shared
// polled lines. Arrival = release-store to a PRIVATE slot line per block.
// Master (block 0, wave 0) polls all 256 slots vectorized (4/lane), then
// scatter-stores to 256 PRIVATE flag lines; each block polls only its own.
// Monotonic phase counter -> no reset, no ABA.
__device__ __forceinline__ void grid_barrier(int* bar, int phase){
    __syncthreads();
    if (threadIdx.x == 0){
        __threadfence();   // release: drain this block's global writes
        __hip_atomic_store(&bar[32 * blockIdx.x], phase,
                           __ATOMIC_RELAXED, __HIP_MEMORY_SCOPE_AGENT);
    }
    if (blockIdx.x == 0 && threadIdx.x < 64){
        int lane = threadIdx.x;
        for (;;){
            int mn = 0x7fffffff;
            #pragma unroll
            for (int q = 0; q < 4; q++){
                int v = __hip_atomic_load(&bar[32 * (lane + 64 * q)],
                                          __ATOMIC_RELAXED, __HIP_MEMORY_SCOPE_AGENT);
                mn = min(mn, v);
            }
            if (__all(mn >= phase)) break;
            __builtin_amdgcn_s_sleep(4);
        }
        __threadfence();   // acquire observed slots; order before flag stores
        #pragma unroll
        for (int q = 0; q < 4; q++)
            __hip_atomic_store(&bar[32 * (GRU_BLOCKS + lane + 64 * q)], phase,
                               __ATOMIC_RELAXED, __HIP_MEMORY_SCOPE_AGENT);
    }
    if (threadIdx.x == 0){
        while (__hip_atomic_load(&bar[32 * (GRU_BLOCKS + blockIdx.x)],
                                 __ATOMIC_RELAXED, __HIP_MEMORY_SCOPE_AGENT) < phase)
            __builtin_amdgcn_s_sleep(4);
        __threadfence();   // acquire: invalidate stale cached h-state
    }
    __syncthreads();
}

// ------- persistent 2-layer GRU, layer-pipelined: ONE barrier per step --------
// Phase p: layer0 step p (reads h0(p-1)) + layer1 step p-1 (reads out1(p-1) =
// h0(p-1) -- same array! -- and h1(p-2)). All inputs are pre-barrier data.
// 16 phases, 15 barriers (was 30). Per-unit h state held in registers.
__global__ __launch_bounds__(256) void k_gru(
        const float* gi0,
        const float* wih1, const float* whh0, const float* whh1,
        const float* bih1, const float* bhh0, const float* bhh1,
        float* h0a, float* h0b, float* h1a, float* h1b,
        float* out, int* bar){
    __shared__ float wsm[18 * HID];      // rows 0-5: whh0, 6-11: wih1, 12-17: whh1
    __shared__ float part[18 * 8 * 32];
    __shared__ float ghl[18 * 32];

    int tid = threadIdx.x;
    int i0 = blockIdx.x * 2;

    #pragma unroll
    for (int r = 0; r < 6; r++){
        int j = (r >> 1) * HID + i0 + (r & 1);
        for (int k = tid; k < HID; k += 256){
            wsm[r * HID + k]        = whh0[(size_t)j * HID + k];
            wsm[(6 + r) * HID + k]  = wih1[(size_t)j * HID + k];
            wsm[(12 + r) * HID + k] = whh1[(size_t)j * HID + k];
        }
    }
    __syncthreads();

    int b = tid & 31, ks = tid >> 5;   // batch lane, k-slice (8 slices of 64)
    int k0 = ks * 64;
    float hs0 = 0.f, hs1 = 0.f;        // registered h state for own unit (tid<64)

    for (int p = 0; p <= SEQ; p++){
        const float* h0r = (p & 1) ? h0a : h0b;   // h0(p-1)  (also = out1(p-1))
        float*       h0w = (p & 1) ? h0b : h0a;   // h0(p)
        const float* h1r = (p & 1) ? h1b : h1a;   // h1(p-2)
        float*       h1w = (p & 1) ? h1a : h1b;   // h1(p-1)

        // ---- merged partial GEMVs: p6 = whh0*h0r, pi = wih1*h0r, ph = whh1*h1r ----
        {
            float pr[6] = {0,0,0,0,0,0}, pi[6] = {0,0,0,0,0,0}, ph[6] = {0,0,0,0,0,0};
            for (int kk = 0; kk < 64; kk += 4){
                int k = k0 + kk;
                float a0 = h0r[(k + 0) * 32 + b];
                float a1 = h0r[(k + 1) * 32 + b];
                float a2 = h0r[(k + 2) * 32 + b];
                float a3 = h0r[(k + 3) * 32 + b];
                float c0 = h1r[(k + 0) * 32 + b];
                float c1 = h1r[(k + 1) * 32 + b];
                float c2 = h1r[(k + 2) * 32 + b];
                float c3 = h1r[(k + 3) * 32 + b];
                #pragma unroll
                for (int r = 0; r < 6; r++){
                    float4 w0 = *(float4*)&wsm[r * HID + k];
                    float4 wi = *(float4*)&wsm[(6 + r) * HID + k];
                    float4 wh = *(float4*)&wsm[(12 + r) * HID + k];
                    pr[r] += a0 * w0.x + a1 * w0.y + a2 * w0.z + a3 * w0.w;
                    pi[r] += a0 * wi.x + a1 * wi.y + a2 * wi.z + a3 * wi.w;
                    ph[r] += c0 * wh.x + c1 * wh.y + c2 * wh.z + c3 * wh.w;
                }
            }
            #pragma unroll
            for (int r = 0; r < 6; r++){
                part[(r * 8 + ks) * 32 + b]        = pr[r];
                part[((6 + r) * 8 + ks) * 32 + b]  = pi[r];
                part[((12 + r) * 8 + ks) * 32 + b] = ph[r];
            }
        }
        __syncthreads();
        {
            int bb = tid & 31;
            for (int r = tid >> 5; r < 18; r += 8){
                float sum = 0.f;
                #pragma unroll
                for (int q = 0; q < 8; q++) sum += part[(r * 8 + q) * 32 + bb];
                ghl[r * 32 + bb] = sum;
            }
        }
        __syncthreads();
        if (tid < 64){
            int l = tid >> 5, bb = tid & 31;
            int i = i0 + l;
            if (p < SEQ){   // layer0 step p
                const float* gi = gi0 + (size_t)(p * BATCH + bb) * G3;
                float ghr = ghl[(0 + l) * 32 + bb] + bhh0[i];
                float ghz = ghl[(2 + l) * 32 + bb] + bhh0[HID + i];
                float ghn = ghl[(4 + l) * 32 + bb] + bhh0[2 * HID + i];
                float rr = sigmoidf(gi[i] + ghr);
                float zz = sigmoidf(gi[HID + i] + ghz);
                float nn = tanhf(gi[2 * HID + i] + rr * ghn);
                hs0 = (1.f - zz) * nn + zz * hs0;
                h0w[i * 32 + bb] = hs0;
            }
            if (p >= 1){    // layer1 step p-1
                float gir = ghl[(6 + l) * 32 + bb]  + bih1[i];
                float giz = ghl[(8 + l) * 32 + bb]  + bih1[HID + i];
                float gin = ghl[(10 + l) * 32 + bb] + bih1[2 * HID + i];
                float ghr = ghl[(12 + l) * 32 + bb] + bhh1[i];
                float ghz = ghl[(14 + l) * 32 + bb] + bhh1[HID + i];
                float ghn = ghl[(16 + l) * 32 + bb] + bhh1[2 * HID + i];
                float rr = sigmoidf(gir + ghr);
                float zz = sigmoidf(giz + ghz);
                float nn = tanhf(gin + rr * ghn);
                hs1 = (1.f - zz) * nn + zz * hs1;
                h1w[i * 32 + bb] = hs1;
                out[(size_t)((p - 1) * BATCH + bb) * HID + i] = hs1;   // out2[p-1,b,i]
            }
        }
        if (p < SEQ) grid_barrier(bar, p + 1);
    }

    // hn from registered state: h0(14), h1(14)
    if (tid < 64){
        int l = tid >> 5, bb = tid & 31;
        int i = i0 + l;
        out[SEQ * BATCH * HID + (size_t)bb * HID + i] = hs0;
        out[SEQ * BATCH * HID + BATCH * HID + (size_t)bb * HID + i] = hs1;
    }
}

extern "C" void kernel_launch(void* const* d_in, const int* in_sizes, int n_in,
                              void* d_out, int out_size, void* d_ws, size_t ws_size,
                              hipStream_t stream){
    (void)in_sizes; (void)n_in; (void)out_size; (void)ws_size;
    const float* x    = (const float*)d_in[0];
    const int*   ei   = (const int*)d_in[1];
    const float* W1   = (const float*)d_in[2];
    const float* b1   = (const float*)d_in[3];
    const float* W2   = (const float*)d_in[4];
    const float* b2   = (const float*)d_in[5];
    const float* wih0 = (const float*)d_in[6];
    const float* whh0 = (const float*)d_in[7];
    const float* bih0 = (const float*)d_in[8];
    const float* bhh0 = (const float*)d_in[9];
    const float* wih1 = (const float*)d_in[10];
    const float* whh1 = (const float*)d_in[11];
    const float* bih1 = (const float*)d_in[12];
    const float* bhh1 = (const float*)d_in[13];
    float* out = (float*)d_out;

    char* w = (char*)d_ws;
    auto alloc = [&](size_t bytes) -> char* {
        char* p = w; w += (bytes + 255) & ~(size_t)255; return p;
    };
    float* dinv   = (float*)alloc(NNODES * 4);
    int*   counts = (int*)  alloc(NNODES * 4);
    int*   offs   = (int*)  alloc((NNODES + 8) * 4);
    int*   fill   = (int*)  alloc(NNODES * 4);
    int*   csr    = (int*)  alloc(NEDGES * 4);
    int*   bar    = (int*)  alloc(BAR_INTS * 4);
    float* h0a    = (float*)alloc(HID * BATCH * 4);
    float* h0b    = (float*)alloc(HID * BATCH * 4);
    float* h1a    = (float*)alloc(HID * BATCH * 4);
    float* h1b    = (float*)alloc(HID * BATCH * 4);
    float* h1s    = (float*)alloc((size_t)SEQ * BATCH * NNODES * 2 * 4);
    float* h2s    = (float*)alloc((size_t)SEQ * BATCH * NNODES * 4);
    float* gbuf   = (float*)alloc((size_t)SEQ * BATCH * NNODES * 4);
    float* gi0    = (float*)alloc((size_t)SEQ * BATCH * G3 * 4);

    k_init <<<64, 256, 0, stream>>>(counts, fill, bar, h0a, h0b, h1a, h1b);
    k_count<<<(NEDGES + 255) / 256, 256, 0, stream>>>(ei, counts);
    k_dinv <<<(NNODES + 255) / 256, 256, 0, stream>>>(counts, dinv);
    k_scan <<<1, 1024, 0, stream>>>(counts, offs);
    k_fill <<<(NEDGES + 255) / 256, 256, 0, stream>>>(ei, offs, fill, csr);

    dim3 gconv((NNODES + 255) / 256, BATCH, SEQ);
    k_conv1<<<gconv, 256, 0, stream>>>(x, W1, dinv, h1s);
    k_agg1 <<<gconv, 256, 0, stream>>>(h1s, offs, csr, dinv, b1, W2, h2s);
    k_agg2 <<<gconv, 256, 0, stream>>>(h2s, offs, csr, dinv, b2, gbuf);

    k_gemm<<<dim3(G3 / 64, 8), 256, 0, stream>>>(gbuf, wih0, bih0, gi0);

    k_gru<<<GRU_BLOCKS, 256, 0, stream>>>(gi0, wih1, whh0, whh1, bih1, bhh0, bhh1,
                                          h0a, h0b, h1a, h1b, out, bar);
}